// Round 4
// baseline (525.284 us; speedup 1.0000x reference)
//
#include <hip/hip_runtime.h>
#include <hip/hip_cooperative_groups.h>

#define Mdim 8
#define Tdim 4000
#define Bdim 128
#define Hdim 512
#define NPER (Tdim*Hdim)
#define EPSG 1e-8f

typedef __attribute__((ext_vector_type(8))) short short8;
typedef __attribute__((ext_vector_type(4))) float floatx4;

static __device__ __forceinline__ float bits2f(unsigned short s) {
  union { unsigned int u; float f; } v; v.u = ((unsigned int)s) << 16; return v.f;
}
static __device__ __forceinline__ unsigned short f2bits(float f) {
  union { float f; unsigned int u; } v; v.f = f;
  unsigned int u = v.u;
  u += 0x7fffu + ((u >> 16) & 1u);   // RNE
  return (unsigned short)(u >> 16);
}
static __device__ __forceinline__ short8 pack8(const float4& a, const float4& b) {
  short8 v;
  v[0]=(short)f2bits(a.x); v[1]=(short)f2bits(a.y); v[2]=(short)f2bits(a.z); v[3]=(short)f2bits(a.w);
  v[4]=(short)f2bits(b.x); v[5]=(short)f2bits(b.y); v[6]=(short)f2bits(b.z); v[7]=(short)f2bits(b.w);
  return v;
}

#define LDS_FENCE() do { \
  asm volatile("s_waitcnt lgkmcnt(0)" ::: "memory"); \
  __builtin_amdgcn_sched_barrier(0); \
} while (0)

struct P {
  const float *x, *w1, *a1, *g1, *b1, *odw, *aodc, *opw, *aopc, *dww, *dwb, *a2, *g2, *b2, *pww;
  float2 *part1, *part2;
  float *const2;
  unsigned short *W2r, *Hbuf, *Ybuf;
  float *out;
};

// smem layout (28672 B total, unioned across phases):
//  phase1: ldsW [64*136] ushort @0 (17408) | ltile [64*72] ushort @17408 (9216) | red [512] f32 @26624 (2048)
//  phase2: s_stats[2] @0 | rsum[4] @8 | rss[4] @24
//  phase4: ltf [64*68] f32 @0 (17408)
#define SMEM_BYTES 28672

// ---------------- phase 1: conv1 GEMM + PReLU + gLN1 partials (baseline-proven)
__device__ __forceinline__ void phase_conv1(const P& p, int task, char* smem) {
  unsigned short* ldsW  = (unsigned short*)smem;
  unsigned short* ltile = (unsigned short*)(smem + 17408);
  float* red = (float*)(smem + 26624);

  const int tid = threadIdx.x;
  const int tile = task % 63;
  const int rem  = task / 63;
  const int hh = rem & 1;
  const int m  = rem >> 1;
  const int t0 = tile * 64;
  const int lane = tid & 63, wv = tid >> 6, quad = lane >> 4, l16 = lane & 15;
  int tr = t0 + wv*16 + l16;
  int trc = tr < Tdim ? tr : Tdim-1;
  const float* xrow = p.x + ((size_t)m*Tdim + trc)*Bdim;
  short8 afr[4];
  #pragma unroll
  for (int ks = 0; ks < 4; ++ks) {
    float4 fa = *(const float4*)&xrow[ks*32 + quad*8];
    float4 fb = *(const float4*)&xrow[ks*32 + quad*8 + 4];
    afr[ks] = pack8(fa, fb);
  }
  const float a1 = p.a1[0];
  float lsum = 0.f, lss = 0.f;

  for (int hc = 0; hc < 4; ++hc) {
    const int h0 = (hh*4 + hc) * 64;
    __syncthreads();
    #pragma unroll
    for (int it = 0; it < 4; ++it) {
      int idx = (it*256 + tid) * 8;
      int r = idx >> 7, c = idx & 127;
      float4 fa = *(const float4*)&p.w1[(size_t)(h0 + r)*Bdim + c];
      float4 fb = *(const float4*)&p.w1[(size_t)(h0 + r)*Bdim + c + 4];
      *(short8*)&ldsW[r*136 + c] = pack8(fa, fb);
    }
    __syncthreads();

    floatx4 acc[4] = {};
    #pragma unroll
    for (int ks = 0; ks < 4; ++ks) {
      #pragma unroll
      for (int nt = 0; nt < 4; ++nt) {
        short8 bfr = *(const short8*)&ldsW[(nt*16 + l16)*136 + ks*32 + quad*8];
        acc[nt] = __builtin_amdgcn_mfma_f32_16x16x32_bf16(afr[ks], bfr, acc[nt], 0, 0, 0);
      }
    }

    #pragma unroll
    for (int nt = 0; nt < 4; ++nt) {
      int hl = nt*16 + l16;
      #pragma unroll
      for (int r = 0; r < 4; ++r) {
        int tl = wv*16 + quad*4 + r;
        float v = acc[nt][r];
        v = v >= 0.f ? v : a1 * v;
        if (t0 + tl < Tdim) { lsum += v; lss += v*v; }
        ltile[tl*72 + hl] = f2bits(v);
      }
    }
    __syncthreads();
    {
      int tr2 = tid >> 2, ck = (tid & 3) * 16;
      int tg = t0 + tr2;
      if (tg < Tdim) {
        unsigned short* dst = &p.Hbuf[((size_t)m*Tdim + tg)*Hdim + h0 + ck];
        *(short8*)&dst[0] = *(const short8*)&ltile[tr2*72 + ck];
        *(short8*)&dst[8] = *(const short8*)&ltile[tr2*72 + ck + 8];
      }
    }
  }

  red[tid] = lsum; red[256 + tid] = lss;
  __syncthreads();
  for (int s = 128; s > 0; s >>= 1) {
    if (tid < s) { red[tid] += red[tid + s]; red[256+tid] += red[256+tid+s]; }
    __syncthreads();
  }
  if (tid == 0)
    p.part1[((size_t)m*2 + hh)*63 + tile] = make_float2(red[0], red[256]);
  __syncthreads();
}

// ---------------- phase 2: fused offsets + deformable dw conv + PReLU2 + gLN2 partials (baseline-proven)
__device__ __forceinline__ void phase_deform(const P& p, int task, char* smem) {
  float* s_stats = (float*)smem;       // [2]
  float* rsum = (float*)smem + 2;      // [4]
  float* rss  = (float*)smem + 6;      // [4]
  const int tid = threadIdx.x, lane = tid & 63, w = tid >> 6;
  const int tx = task % 500;
  const int m  = task / 500;
  const int tb = tx*8 + w*2;
  const int c8 = lane*8;
  const unsigned short* base = p.Hbuf + (size_t)m*Tdim*Hdim;

  __syncthreads();   // smem reuse guard across consecutive tasks

  short8 hrow[2][3];
  #pragma unroll
  for (int tt = 0; tt < 2; ++tt) {
    int t = tb + tt;
    int tm1 = (t == 0) ? 1 : t-1;
    int tp1 = (t == Tdim-1) ? Tdim-2 : t+1;
    hrow[tt][0] = *(const short8*)&base[(size_t)tm1*Hdim + c8];
    hrow[tt][1] = *(const short8*)&base[(size_t)t  *Hdim + c8];
    hrow[tt][2] = *(const short8*)&base[(size_t)tp1*Hdim + c8];
  }
  float g1v[8], b1v[8];
  #pragma unroll
  for (int j = 0; j < 8; j += 4) {
    *(float4*)&g1v[j] = *(const float4*)&p.g1[c8 + j];
    *(float4*)&b1v[j] = *(const float4*)&p.b1[c8 + j];
  }

  if (tid < 64) {
    float s = 0.f, q = 0.f;
    for (int i = lane; i < 126; i += 64) {
      float2 pp = p.part1[(size_t)m*126 + i];
      s += pp.x; q += pp.y;
    }
    #pragma unroll
    for (int st = 32; st > 0; st >>= 1) { s += __shfl_xor(s, st); q += __shfl_xor(q, st); }
    if (lane == 0) { s_stats[0] = s; s_stats[1] = q; }
  }
  __syncthreads();
  const float invn = 1.0f/(float)NPER;
  const float mean1 = s_stats[0]*invn;
  const float var1  = fmaxf(s_stats[1]*invn - mean1*mean1, 0.f);
  const float inv1  = 1.0f/sqrtf(var1 + EPSG);

  float oa[2][3] = {};
  {
    const float aodc = p.aodc[0];
    float wod[24], q0v[8], q1v[8], q2v[8];
    #pragma unroll
    for (int j = 0; j < 8; j += 4) {
      *(float4*)&q0v[j] = *(const float4*)&p.opw[c8 + j];
      *(float4*)&q1v[j] = *(const float4*)&p.opw[Hdim + c8 + j];
      *(float4*)&q2v[j] = *(const float4*)&p.opw[2*Hdim + c8 + j];
    }
    #pragma unroll
    for (int j = 0; j < 24; j += 4)
      *(float4*)&wod[j] = *(const float4*)&p.odw[c8*3 + j];

    #pragma unroll
    for (int j = 0; j < 8; ++j) {
      float A = g1v[j] * inv1;
      float C = b1v[j] - mean1*A;
      #pragma unroll
      for (int tt = 0; tt < 2; ++tt) {
        float fm = fmaf(A, bits2f((unsigned short)hrow[tt][0][j]), C);
        float fz = fmaf(A, bits2f((unsigned short)hrow[tt][1][j]), C);
        float fp = fmaf(A, bits2f((unsigned short)hrow[tt][2][j]), C);
        float d = fm*wod[j*3+0] + fz*wod[j*3+1] + fp*wod[j*3+2];
        d = d >= 0.f ? d : aodc*d;
        oa[tt][0] = fmaf(d, q0v[j], oa[tt][0]);
        oa[tt][1] = fmaf(d, q1v[j], oa[tt][1]);
        oa[tt][2] = fmaf(d, q2v[j], oa[tt][2]);
      }
    }
    #pragma unroll
    for (int s = 32; s > 0; s >>= 1) {
      #pragma unroll
      for (int tt = 0; tt < 2; ++tt) {
        oa[tt][0] += __shfl_xor(oa[tt][0], s);
        oa[tt][1] += __shfl_xor(oa[tt][1], s);
        oa[tt][2] += __shfl_xor(oa[tt][2], s);
      }
    }
  }

  const float aopc = p.aopc[0];
  const float a2   = p.a2[0];
  int I0[2][3], I1[2][3]; float G0[2][3], G1[2][3], GS[2][3];
  #pragma unroll
  for (int tt = 0; tt < 2; ++tt) {
    const float tf = (float)(tb + tt);
    #pragma unroll
    for (int k = 0; k < 3; ++k) {
      float off = oa[tt][k];
      off = off >= 0.f ? off : aopc*off;
      float pos = tf + (float)(2*k) + off;
      pos = fminf(fmaxf(pos, tf), tf + 4.0f);
      int U = (int)floorf(pos);
      if (U > Tdim + 2) U = Tdim + 2;        // Lp-2
      float Uf = (float)U;
      G0[tt][k] = fmaxf(0.f, 1.f - fabsf(Uf - pos));
      G1[tt][k] = fmaxf(0.f, 1.f - fabsf(Uf + 1.f - pos));
      GS[tt][k] = G0[tt][k] + G1[tt][k];
      int ia = U - 2; ia = ia < 0 ? -ia : ia; if (ia > Tdim-1) ia = 2*(Tdim-1) - ia;
      int ib = U - 1; ib = ib < 0 ? -ib : ib; if (ib > Tdim-1) ib = 2*(Tdim-1) - ib;
      I0[tt][k] = ia; I1[tt][k] = ib;
    }
  }

  short8 s0v[2][3], s1v[2][3];
  #pragma unroll
  for (int tt = 0; tt < 2; ++tt)
    #pragma unroll
    for (int k = 0; k < 3; ++k) {
      s0v[tt][k] = *(const short8*)&base[(size_t)I0[tt][k]*Hdim + c8];
      s1v[tt][k] = *(const short8*)&base[(size_t)I1[tt][k]*Hdim + c8];
    }

  float bv[8], wd[24];
  #pragma unroll
  for (int j = 0; j < 8; j += 4)
    *(float4*)&bv[j] = *(const float4*)&p.dwb[c8 + j];
  #pragma unroll
  for (int j = 0; j < 24; j += 4)
    *(float4*)&wd[j] = *(const float4*)&p.dww[c8*3 + j];

  float lsum = 0.f, lss = 0.f;
  short8 yv[2];
  #pragma unroll
  for (int j = 0; j < 8; ++j) {
    float A = g1v[j] * inv1;
    float C = b1v[j] - mean1*A;
    float w0 = wd[j*3+0], w1 = wd[j*3+1], w2 = wd[j*3+2];
    #pragma unroll
    for (int tt = 0; tt < 2; ++tt) {
      float ybase = fmaf(C, w0*GS[tt][0] + w1*GS[tt][1] + w2*GS[tt][2], bv[j]);
      float t0s = fmaf(G1[tt][0], bits2f((unsigned short)s1v[tt][0][j]), G0[tt][0]*bits2f((unsigned short)s0v[tt][0][j]));
      float t1s = fmaf(G1[tt][1], bits2f((unsigned short)s1v[tt][1][j]), G0[tt][1]*bits2f((unsigned short)s0v[tt][1][j]));
      float t2s = fmaf(G1[tt][2], bits2f((unsigned short)s1v[tt][2][j]), G0[tt][2]*bits2f((unsigned short)s0v[tt][2][j]));
      float acc = w0*t0s + w1*t1s + w2*t2s;
      float y = fmaf(A, acc, ybase);
      float pp = y >= 0.f ? y : a2*y;
      lsum += pp; lss += pp*pp;
      yv[tt][j] = (short)f2bits(pp);
    }
  }
  #pragma unroll
  for (int tt = 0; tt < 2; ++tt)
    *(short8*)&p.Ybuf[((size_t)m*Tdim + tb + tt)*Hdim + c8] = yv[tt];

  #pragma unroll
  for (int s = 32; s > 0; s >>= 1) {
    lsum += __shfl_xor(lsum, s);
    lss  += __shfl_xor(lss, s);
  }
  if (lane == 0) { rsum[w] = lsum; rss[w] = lss; }
  __syncthreads();
  if (tid == 0)
    p.part2[(size_t)m*500 + tx] =
      make_float2(rsum[0]+rsum[1]+rsum[2]+rsum[3], rss[0]+rss[1]+rss[2]+rss[3]);
}

// ---------------- phase 3: reduce part2 + fold gLN2 into pointwise weights; W2 in fragment order
__device__ __forceinline__ void phase_w2(const P& p, int task) {
  const int tid = threadIdx.x;
  if (tid >= 64) return;
  const int m = task >> 7, b = task & 127;

  float s = 0.f, q = 0.f;
  for (int i = tid; i < 500; i += 64) {
    float2 pp = p.part2[(size_t)m*500 + i];
    s += pp.x; q += pp.y;
  }
  #pragma unroll
  for (int st = 32; st > 0; st >>= 1) { s += __shfl_xor(s, st); q += __shfl_xor(q, st); }

  const float invn = 1.0f/(float)NPER;
  const float mean2 = s*invn;
  const float var2  = fmaxf(q*invn - mean2*mean2, 0.f);
  const float inv2  = 1.0f/sqrtf(var2 + EPSG);

  const int j8 = tid*8;
  float g2v[8], b2v[8], pv[8];
  #pragma unroll
  for (int j = 0; j < 8; j += 4) {
    *(float4*)&g2v[j] = *(const float4*)&p.g2[j8 + j];
    *(float4*)&b2v[j] = *(const float4*)&p.b2[j8 + j];
    *(float4*)&pv[j]  = *(const float4*)&p.pww[(size_t)b*Hdim + j8 + j];
  }
  float csum = 0.f;
  short8 wv8;
  #pragma unroll
  for (int j = 0; j < 8; ++j) {
    float A = g2v[j] * inv2;
    float C = b2v[j] - mean2*A;
    csum = fmaf(C, pv[j], csum);
    wv8[j] = (short)f2bits(A*pv[j]);
  }
  {
    int half = b >> 6, nt = (b >> 4) & 3, l16 = b & 15;
    int kc = tid >> 4, ks = (tid >> 2) & 3, quad = tid & 3;
    int lane = quad*16 + l16;
    size_t f = ((((size_t)(m*2 + half)*4 + kc)*4 + ks)*4 + nt);
    *(short8*)&p.W2r[(f*64 + lane)*8] = wv8;
  }

  #pragma unroll
  for (int st = 32; st > 0; st >>= 1) csum += __shfl_down(csum, st);
  if (tid == 0) p.const2[m*Bdim + b] = csum;
}

// ---------------- phase 4: final GEMM Ybuf @ W2^T + const2 + residual -> out f32
__device__ __forceinline__ void phase_out(const P& p, int task, char* smem) {
  float* ltf = (float*)smem;           // 64*68 floats
  const int tid = threadIdx.x;
  const int tile = task % 63;
  const int rem = task / 63;
  const int half = rem & 1;
  const int m = rem >> 1;
  const int t0 = tile*64;
  const int n0 = half*64;
  const int lane = tid & 63, wv = tid >> 6, quad = lane >> 4, l16 = lane & 15;
  int tr = t0 + wv*16 + l16;
  int trc = tr < Tdim ? tr : Tdim-1;
  const unsigned short* arow = p.Ybuf + ((size_t)m*Tdim + trc)*Hdim;
  const short8* wf = (const short8*)p.W2r + (size_t)(m*2 + half)*64*64 + lane;

  floatx4 acc[4] = {};
  #pragma unroll
  for (int kc = 0; kc < 4; ++kc)
    #pragma unroll
    for (int ks = 0; ks < 4; ++ks) {
      short8 afr = *(const short8*)&arow[kc*128 + ks*32 + quad*8];
      #pragma unroll
      for (int nt = 0; nt < 4; ++nt)
        acc[nt] = __builtin_amdgcn_mfma_f32_16x16x32_bf16(
            afr, wf[((kc*4 + ks)*4 + nt)*64], acc[nt], 0, 0, 0);
    }

  #pragma unroll
  for (int nt = 0; nt < 4; ++nt) {
    int bl = nt*16 + l16;
    float cb = p.const2[m*Bdim + n0 + bl];
    #pragma unroll
    for (int r = 0; r < 4; ++r) {
      int tl = wv*16 + quad*4 + r;
      ltf[tl*68 + bl] = acc[nt][r] + cb;
    }
  }
  LDS_FENCE();   // wave-private transpose: write -> read
  {
    int tr2 = tid >> 2, ck = (tid & 3) * 16;
    int tg = t0 + tr2;
    if (tg < Tdim) {
      const float* xr = &p.x[((size_t)m*Tdim + tg)*Bdim + n0 + ck];
      float* orow = &p.out[((size_t)m*Tdim + tg)*Bdim + n0 + ck];
      #pragma unroll
      for (int j = 0; j < 4; ++j) {
        float4 v = *(const float4*)&ltf[tr2*68 + ck + j*4];
        float4 rx = *(const float4*)&xr[j*4];
        v.x += rx.x; v.y += rx.y; v.z += rx.z; v.w += rx.w;
        *(float4*)&orow[j*4] = v;
      }
    }
  }
  LDS_FENCE();   // reads drained before next task overwrites ltf
}

// ---------------- cooperative mega-kernel: 4 phases, 3 grid syncs, 1 launch
__global__ __launch_bounds__(256, 4) void k_fused(P p) {
  __shared__ __align__(16) char smem[SMEM_BYTES];
  cooperative_groups::grid_group g = cooperative_groups::this_grid();

  for (int t = blockIdx.x; t < 1008; t += gridDim.x) phase_conv1(p, t, smem);
  __threadfence();
  g.sync();
  for (int t = blockIdx.x; t < 4000; t += gridDim.x) phase_deform(p, t, smem);
  __threadfence();
  g.sync();
  for (int t = blockIdx.x; t < 1024; t += gridDim.x) phase_w2(p, t);
  __threadfence();
  g.sync();
  for (int t = blockIdx.x; t < 1008; t += gridDim.x) phase_out(p, t, smem);
}

// ---------------- fallback wrappers (non-cooperative), identical math
__global__ __launch_bounds__(256, 4) void k_p1(P p) {
  __shared__ __align__(16) char smem[SMEM_BYTES];
  phase_conv1(p, blockIdx.x, smem);
}
__global__ __launch_bounds__(256, 4) void k_p2(P p) {
  __shared__ __align__(16) char smem[SMEM_BYTES];
  phase_deform(p, blockIdx.x, smem);
}
__global__ __launch_bounds__(256, 4) void k_p3(P p) {
  phase_w2(p, blockIdx.x);
}
__global__ __launch_bounds__(256, 4) void k_p4(P p) {
  __shared__ __align__(16) char smem[SMEM_BYTES];
  phase_out(p, blockIdx.x, smem);
}

extern "C" void kernel_launch(void* const* d_in, const int* in_sizes, int n_in,
                              void* d_out, int out_size, void* d_ws, size_t ws_size,
                              hipStream_t stream)
{
  (void)in_sizes; (void)n_in; (void)out_size; (void)ws_size;

  char* ws = (char*)d_ws;
  const size_t OFF_P1 = 0;          // part1 [8,126] float2: 8064 B
  const size_t OFF_P2 = 8192;       // part2 [8,500] float2: 32000 B
  const size_t OFF_C2 = 40960;      // const2 [8,128] f32: 4096 B
  const size_t OFF_W2 = 45056;      // W2r [8,128,512] bf16 fragment order: 1048576 B
  const size_t OFF_H  = 1093632;    // Hbuf [8,4000,512] bf16: 32768000 B
  const size_t OFF_Y  = 33861632;   // Ybuf [8,4000,512] bf16: 32768000 B

  P hp;
  hp.x    = (const float*)d_in[0];
  hp.w1   = (const float*)d_in[1];
  hp.a1   = (const float*)d_in[2];
  hp.g1   = (const float*)d_in[3];
  hp.b1   = (const float*)d_in[4];
  hp.odw  = (const float*)d_in[5];
  hp.aodc = (const float*)d_in[6];
  hp.opw  = (const float*)d_in[7];
  hp.aopc = (const float*)d_in[8];
  hp.dww  = (const float*)d_in[9];
  hp.dwb  = (const float*)d_in[10];
  hp.a2   = (const float*)d_in[11];
  hp.g2   = (const float*)d_in[12];
  hp.b2   = (const float*)d_in[13];
  hp.pww  = (const float*)d_in[14];
  hp.part1  = (float2*)(ws + OFF_P1);
  hp.part2  = (float2*)(ws + OFF_P2);
  hp.const2 = (float*)(ws + OFF_C2);
  hp.W2r  = (unsigned short*)(ws + OFF_W2);
  hp.Hbuf = (unsigned short*)(ws + OFF_H);
  hp.Ybuf = (unsigned short*)(ws + OFF_Y);
  hp.out  = (float*)d_out;

  // Decide launch mode once: cooperative grid sized to guaranteed co-residency.
  static int coopGrid = -2;   // -2 = unknown, -1 = fallback, >0 = grid size
  if (coopGrid == -2) {
    int maxb = 0;
    if (hipOccupancyMaxActiveBlocksPerMultiprocessor(&maxb, (const void*)k_fused, 256, 0)
          == hipSuccess && maxb > 0) {
      long g = (long)maxb * 256;             // 256 CUs on MI355X
      if (g > 1024) g = 1024;
      coopGrid = (int)g;
    } else {
      coopGrid = -1;
    }
  }

  bool launched = false;
  if (coopGrid > 0) {
    void* params[] = { (void*)&hp };
    if (hipLaunchCooperativeKernel((const void*)k_fused, dim3(coopGrid), dim3(256),
                                   params, 0, stream) == hipSuccess) {
      launched = true;
    } else {
      coopGrid = -1;   // cooperative rejected: fall back permanently
    }
  }
  if (!launched) {
    k_p1<<<dim3(1008), 256, 0, stream>>>(hp);
    k_p2<<<dim3(4000), 256, 0, stream>>>(hp);
    k_p3<<<dim3(1024), 256, 0, stream>>>(hp);
    k_p4<<<dim3(1008), 256, 0, stream>>>(hp);
  }
}

// Round 5
// 166.229 us; speedup vs baseline: 3.1600x; 3.1600x over previous
//
#include <hip/hip_runtime.h>

#define Mdim 8
#define Tdim 4000
#define Bdim 128
#define Hdim 512
#define NPER (Tdim*Hdim)
#define EPSG 1e-8f

typedef __attribute__((ext_vector_type(8))) short short8;
typedef __attribute__((ext_vector_type(4))) float floatx4;

static __device__ __forceinline__ float bits2f(unsigned short s) {
  union { unsigned int u; float f; } v; v.u = ((unsigned int)s) << 16; return v.f;
}
static __device__ __forceinline__ unsigned short f2bits(float f) {
  union { float f; unsigned int u; } v; v.f = f;
  unsigned int u = v.u;
  u += 0x7fffu + ((u >> 16) & 1u);   // RNE
  return (unsigned short)(u >> 16);
}
static __device__ __forceinline__ short8 pack8(const float4& a, const float4& b) {
  short8 v;
  v[0]=(short)f2bits(a.x); v[1]=(short)f2bits(a.y); v[2]=(short)f2bits(a.z); v[3]=(short)f2bits(a.w);
  v[4]=(short)f2bits(b.x); v[5]=(short)f2bits(b.y); v[6]=(short)f2bits(b.z); v[7]=(short)f2bits(b.w);
  return v;
}

// wave-local LDS fence: all lanes' ds ops drained; lockstep => covers cross-lane within wave
#define LDS_FENCE() do { \
  asm volatile("s_waitcnt lgkmcnt(0)" ::: "memory"); \
  __builtin_amdgcn_sched_barrier(0); \
} while (0)

// ---------------- K0: one-time weight prep.
// blocks 0..31:  w1 [512,128] f32 -> fragment-ordered bf16 w1r.
// blocks 32..63: W2g[b,h] = pww[b,h]*g2[h] -> fragment-ordered bf16 (m-independent!);
//                S[b] = sum_h pww*g2, B2s[b] = sum_h pww*b2 (f32).
__global__ __launch_bounds__(256) void k_prep(
    const float* __restrict__ w1,
    const float* __restrict__ pww,
    const float* __restrict__ g2w,
    const float* __restrict__ b2w,
    unsigned short* __restrict__ w1r,
    unsigned short* __restrict__ W2g,
    float* __restrict__ Sv,
    float* __restrict__ B2s)
{
  const int tid = threadIdx.x;
  if (blockIdx.x < 32) {
    int i = blockIdx.x*256 + tid;            // 8192 short8 fragments
    int lane = i & 63, f = i >> 6;
    int nt = f & 3, ks = (f >> 2) & 3, hc = f >> 4;
    int h = hc*64 + nt*16 + (lane & 15);
    int c = ks*32 + (lane >> 4)*8;
    const float* src = &w1[(size_t)h*Bdim + c];
    float4 a = *(const float4*)src;
    float4 b = *(const float4*)(src + 4);
    *(short8*)&w1r[(size_t)i*8] = pack8(a, b);
  } else {
    const int b = (blockIdx.x - 32)*4 + (tid >> 6);   // one wave per b
    const int sub = tid & 63;
    const int j8 = sub*8;
    float pv[8], g2v[8], b2v[8];
    #pragma unroll
    for (int j = 0; j < 8; j += 4) {
      *(float4*)&pv[j]  = *(const float4*)&pww[(size_t)b*Hdim + j8 + j];
      *(float4*)&g2v[j] = *(const float4*)&g2w[j8 + j];
      *(float4*)&b2v[j] = *(const float4*)&b2w[j8 + j];
    }
    float sS = 0.f, sB = 0.f;
    short8 wv8;
    #pragma unroll
    for (int j = 0; j < 8; ++j) {
      float pg = pv[j]*g2v[j];
      sS += pg;
      sB += pv[j]*b2v[j];
      wv8[j] = (short)f2bits(pg);
    }
    // fragment address (m-independent): half=b>>6, nt=(b>>4)&3, l16=b&15;
    // kc=sub>>4, ks=(sub>>2)&3, quad=sub&3
    {
      int half = b >> 6, nt = (b >> 4) & 3, l16 = b & 15;
      int kc = sub >> 4, ks = (sub >> 2) & 3, quad = sub & 3;
      int lane = quad*16 + l16;
      size_t f = (((size_t)(half*4 + kc)*4 + ks)*4 + nt);
      *(short8*)&W2g[(f*64 + lane)*8] = wv8;
    }
    #pragma unroll
    for (int st = 32; st > 0; st >>= 1) { sS += __shfl_xor(sS, st); sB += __shfl_xor(sB, st); }
    if (sub == 0) { Sv[b] = sS; B2s[b] = sB; }
  }
}

// ---------------- K1: conv1 GEMM + PReLU + gLN1 partials -> Hbuf [M,T,H] bf16
// 32-t tiles (grid 1000); waves split h-halves; x read once; no block barriers in hot loop.
// (R3-proven variant.)
__global__ __launch_bounds__(256) void k_conv1(
    const float* __restrict__ x,
    const unsigned short* __restrict__ w1r,
    const float* __restrict__ a1p,
    unsigned short* __restrict__ Hbuf,
    float2* __restrict__ part1)
{
  __shared__ __align__(16) unsigned short ltile[4][16*72];
  __shared__ float red[512];

  const int tid = threadIdx.x;
  const int t0 = blockIdx.x * 32;
  const int m  = blockIdx.y;
  const int lane = tid & 63, w = tid >> 6, quad = lane >> 4, l16 = lane & 15;
  const int tsub = w & 1, hh = w >> 1;
  const int tbase = t0 + tsub*16;            // 125*32 = 4000 exactly: no clamps needed
  const float* xrow = x + ((size_t)m*Tdim + tbase + l16)*Bdim;
  short8 afr[4];
  #pragma unroll
  for (int ks = 0; ks < 4; ++ks) {
    float4 fa = *(const float4*)&xrow[ks*32 + quad*8];
    float4 fb = *(const float4*)&xrow[ks*32 + quad*8 + 4];
    afr[ks] = pack8(fa, fb);
  }

  const float a1 = a1p[0];
  const short8* wf = (const short8*)w1r + lane;
  float lsum = 0.f, lss = 0.f;

  #pragma unroll
  for (int hc4 = 0; hc4 < 4; ++hc4) {
    const int hcg = hh*4 + hc4;
    floatx4 acc[4] = {};
    #pragma unroll
    for (int ks = 0; ks < 4; ++ks)
      #pragma unroll
      for (int nt = 0; nt < 4; ++nt)
        acc[nt] = __builtin_amdgcn_mfma_f32_16x16x32_bf16(
            afr[ks], wf[(hcg*16 + ks*4 + nt)*64], acc[nt], 0, 0, 0);

    #pragma unroll
    for (int nt = 0; nt < 4; ++nt) {
      int hl = nt*16 + l16;                  // C/D: col = lane&15
      #pragma unroll
      for (int r = 0; r < 4; ++r) {
        int tl = quad*4 + r;                 // C/D: row = quad*4+reg
        float v = acc[nt][r];
        v = v >= 0.f ? v : a1 * v;
        lsum += v; lss += v*v;
        ltile[w][tl*72 + hl] = f2bits(v);
      }
    }
    LDS_FENCE();   // wave-private transpose tile: writes -> cross-lane reads
    {
      int row = lane >> 2, ck = (lane & 3) * 16;
      unsigned short* dst = &Hbuf[((size_t)m*Tdim + tbase + row)*Hdim + hcg*64 + ck];
      *(short8*)&dst[0] = *(const short8*)&ltile[w][row*72 + ck];
      *(short8*)&dst[8] = *(const short8*)&ltile[w][row*72 + ck + 8];
    }
    LDS_FENCE();   // reads drained before next hc overwrites
  }

  red[tid] = lsum; red[256 + tid] = lss;
  __syncthreads();
  for (int s = 128; s > 0; s >>= 1) {
    if (tid < s) { red[tid] += red[tid + s]; red[256+tid] += red[256+tid+s]; }
    __syncthreads();
  }
  if (tid == 0)
    part1[(size_t)m*125 + blockIdx.x] = make_float2(red[0], red[256]);
}

// ---------------- K2: fused offsets + deformable dw conv + PReLU2 + gLN2 partials -> Ybuf
// BASELINE-proven variant: one wave per (m, 2 consecutive t), direct global gathers.
__global__ __launch_bounds__(256) void k_deform(
    const unsigned short* __restrict__ Hbuf,
    const float2* __restrict__ part1,
    const float* __restrict__ g1w,
    const float* __restrict__ b1w,
    const float* __restrict__ odw,
    const float* __restrict__ aodcp,
    const float* __restrict__ opw,
    const float* __restrict__ aopcp,
    const float* __restrict__ dww,
    const float* __restrict__ dwb,
    const float* __restrict__ a2p,
    unsigned short* __restrict__ Ybuf,
    float2* __restrict__ part2)
{
  __shared__ float s_stats[2];
  __shared__ float rsum[4], rss[4];
  const int tid = threadIdx.x, lane = tid & 63, w = tid >> 6;
  const int tb = blockIdx.x*8 + w*2;       // grid.x = 500; wave handles t = tb, tb+1
  const int m = blockIdx.y;
  const int c8 = lane*8;
  const unsigned short* base = Hbuf + (size_t)m*Tdim*Hdim;

  // issue offset-branch row loads EARLY (independent of stats barrier)
  short8 hrow[2][3];
  #pragma unroll
  for (int tt = 0; tt < 2; ++tt) {
    int t = tb + tt;
    int tm1 = (t == 0) ? 1 : t-1;
    int tp1 = (t == Tdim-1) ? Tdim-2 : t+1;
    hrow[tt][0] = *(const short8*)&base[(size_t)tm1*Hdim + c8];
    hrow[tt][1] = *(const short8*)&base[(size_t)t  *Hdim + c8];
    hrow[tt][2] = *(const short8*)&base[(size_t)tp1*Hdim + c8];
  }
  float g1v[8], b1v[8];
  #pragma unroll
  for (int j = 0; j < 8; j += 4) {
    *(float4*)&g1v[j] = *(const float4*)&g1w[c8 + j];
    *(float4*)&b1v[j] = *(const float4*)&b1w[c8 + j];
  }

  // inline reduce of part1 (125 entries) -> stats1
  if (tid < 64) {
    float s = 0.f, q = 0.f;
    for (int i = lane; i < 125; i += 64) {
      float2 p = part1[(size_t)m*125 + i];
      s += p.x; q += p.y;
    }
    #pragma unroll
    for (int st = 32; st > 0; st >>= 1) { s += __shfl_xor(s, st); q += __shfl_xor(q, st); }
    if (lane == 0) { s_stats[0] = s; s_stats[1] = q; }
  }
  __syncthreads();
  const float invn = 1.0f/(float)NPER;
  const float mean1 = s_stats[0]*invn;
  const float var1  = fmaxf(s_stats[1]*invn - mean1*mean1, 0.f);
  const float inv1  = 1.0f/sqrtf(var1 + EPSG);

  // ---- offset branch for both t ----
  float oa[2][3] = {};
  {
    const float aodc = aodcp[0];
    float wod[24], q0v[8], q1v[8], q2v[8];
    #pragma unroll
    for (int j = 0; j < 8; j += 4) {
      *(float4*)&q0v[j] = *(const float4*)&opw[c8 + j];
      *(float4*)&q1v[j] = *(const float4*)&opw[Hdim + c8 + j];
      *(float4*)&q2v[j] = *(const float4*)&opw[2*Hdim + c8 + j];
    }
    #pragma unroll
    for (int j = 0; j < 24; j += 4)
      *(float4*)&wod[j] = *(const float4*)&odw[c8*3 + j];

    #pragma unroll
    for (int j = 0; j < 8; ++j) {
      float A = g1v[j] * inv1;
      float C = b1v[j] - mean1*A;
      #pragma unroll
      for (int tt = 0; tt < 2; ++tt) {
        float fm = fmaf(A, bits2f((unsigned short)hrow[tt][0][j]), C);
        float fz = fmaf(A, bits2f((unsigned short)hrow[tt][1][j]), C);
        float fp = fmaf(A, bits2f((unsigned short)hrow[tt][2][j]), C);
        float d = fm*wod[j*3+0] + fz*wod[j*3+1] + fp*wod[j*3+2];
        d = d >= 0.f ? d : aodc*d;
        oa[tt][0] = fmaf(d, q0v[j], oa[tt][0]);
        oa[tt][1] = fmaf(d, q1v[j], oa[tt][1]);
        oa[tt][2] = fmaf(d, q2v[j], oa[tt][2]);
      }
    }
    #pragma unroll
    for (int s = 32; s > 0; s >>= 1) {
      #pragma unroll
      for (int tt = 0; tt < 2; ++tt) {
        oa[tt][0] += __shfl_xor(oa[tt][0], s);
        oa[tt][1] += __shfl_xor(oa[tt][1], s);
        oa[tt][2] += __shfl_xor(oa[tt][2], s);
      }
    }
  }

  // ---- tap params (wave-uniform) + gathers for both t ----
  const float aopc = aopcp[0];
  const float a2   = a2p[0];
  int I0[2][3], I1[2][3]; float G0[2][3], G1[2][3], GS[2][3];
  #pragma unroll
  for (int tt = 0; tt < 2; ++tt) {
    const float tf = (float)(tb + tt);
    #pragma unroll
    for (int k = 0; k < 3; ++k) {
      float off = oa[tt][k];
      off = off >= 0.f ? off : aopc*off;
      float pos = tf + (float)(2*k) + off;
      pos = fminf(fmaxf(pos, tf), tf + 4.0f);
      int U = (int)floorf(pos);
      if (U > Tdim + 2) U = Tdim + 2;        // Lp-2
      float Uf = (float)U;
      G0[tt][k] = fmaxf(0.f, 1.f - fabsf(Uf - pos));
      G1[tt][k] = fmaxf(0.f, 1.f - fabsf(Uf + 1.f - pos));
      GS[tt][k] = G0[tt][k] + G1[tt][k];
      int ia = U - 2; ia = ia < 0 ? -ia : ia; if (ia > Tdim-1) ia = 2*(Tdim-1) - ia;
      int ib = U - 1; ib = ib < 0 ? -ib : ib; if (ib > Tdim-1) ib = 2*(Tdim-1) - ib;
      I0[tt][k] = ia; I1[tt][k] = ib;
    }
  }

  // issue ALL 12 gather loads up front (both t's) for maximum MLP
  short8 s0v[2][3], s1v[2][3];
  #pragma unroll
  for (int tt = 0; tt < 2; ++tt)
    #pragma unroll
    for (int k = 0; k < 3; ++k) {
      s0v[tt][k] = *(const short8*)&base[(size_t)I0[tt][k]*Hdim + c8];
      s1v[tt][k] = *(const short8*)&base[(size_t)I1[tt][k]*Hdim + c8];
    }

  float bv[8], wd[24];
  #pragma unroll
  for (int j = 0; j < 8; j += 4)
    *(float4*)&bv[j] = *(const float4*)&dwb[c8 + j];
  #pragma unroll
  for (int j = 0; j < 24; j += 4)
    *(float4*)&wd[j] = *(const float4*)&dww[c8*3 + j];

  float lsum = 0.f, lss = 0.f;
  short8 yv[2];
  #pragma unroll
  for (int j = 0; j < 8; ++j) {
    float A = g1v[j] * inv1;
    float C = b1v[j] - mean1*A;
    float w0 = wd[j*3+0], w1 = wd[j*3+1], w2 = wd[j*3+2];
    #pragma unroll
    for (int tt = 0; tt < 2; ++tt) {
      float ybase = fmaf(C, w0*GS[tt][0] + w1*GS[tt][1] + w2*GS[tt][2], bv[j]);
      float t0s = fmaf(G1[tt][0], bits2f((unsigned short)s1v[tt][0][j]), G0[tt][0]*bits2f((unsigned short)s0v[tt][0][j]));
      float t1s = fmaf(G1[tt][1], bits2f((unsigned short)s1v[tt][1][j]), G0[tt][1]*bits2f((unsigned short)s0v[tt][1][j]));
      float t2s = fmaf(G1[tt][2], bits2f((unsigned short)s1v[tt][2][j]), G0[tt][2]*bits2f((unsigned short)s0v[tt][2][j]));
      float acc = w0*t0s + w1*t1s + w2*t2s;
      float y = fmaf(A, acc, ybase);
      float p = y >= 0.f ? y : a2*y;
      lsum += p; lss += p*p;
      yv[tt][j] = (short)f2bits(p);
    }
  }
  #pragma unroll
  for (int tt = 0; tt < 2; ++tt)
    *(short8*)&Ybuf[((size_t)m*Tdim + tb + tt)*Hdim + c8] = yv[tt];

  #pragma unroll
  for (int s = 32; s > 0; s >>= 1) {
    lsum += __shfl_xor(lsum, s);
    lss  += __shfl_xor(lss, s);
  }
  if (lane == 0) { rsum[w] = lsum; rss[w] = lss; }
  __syncthreads();
  if (tid == 0)
    part2[(size_t)m*500 + blockIdx.x] =
      make_float2(rsum[0]+rsum[1]+rsum[2]+rsum[3], rss[0]+rss[1]+rss[2]+rss[3]);
}

// ---------------- K3: final GEMM Ybuf @ (pw*g2)^T; gLN2 applied as scalar affine epilogue.
// Inline part2 reduction (500 entries, L2-hot); W2g fragment-ordered direct from global.
__global__ __launch_bounds__(256) void k_out(
    const unsigned short* __restrict__ Ybuf,
    const unsigned short* __restrict__ W2g,
    const float2* __restrict__ part2,
    const float* __restrict__ Sv,
    const float* __restrict__ B2s,
    const float* __restrict__ x,
    float* __restrict__ out)
{
  __shared__ __align__(16) float ltf[64*68];
  __shared__ float rsA[4], rsB[4];
  const int tid = threadIdx.x;
  const int t0 = blockIdx.x*64;
  const int half = blockIdx.y;
  const int n0 = half*64;
  const int m  = blockIdx.z;
  const int lane = tid & 63, wv = tid >> 6, quad = lane >> 4, l16 = lane & 15;

  // ---- inline gLN2 stats: all 4 waves split the 500 partials ----
  {
    float s = 0.f, q = 0.f;
    for (int i = tid; i < 500; i += 256) {
      float2 p = part2[(size_t)m*500 + i];
      s += p.x; q += p.y;
    }
    #pragma unroll
    for (int st = 32; st > 0; st >>= 1) { s += __shfl_xor(s, st); q += __shfl_xor(q, st); }
    if (lane == 0) { rsA[wv] = s; rsB[wv] = q; }
  }

  int tr = t0 + wv*16 + l16;
  int trc = tr < Tdim ? tr : Tdim-1;
  const unsigned short* arow = Ybuf + ((size_t)m*Tdim + trc)*Hdim;
  const short8* wf = (const short8*)W2g + (size_t)half*64*64 + lane;

  floatx4 acc[4] = {};
  #pragma unroll
  for (int kc = 0; kc < 4; ++kc)
    #pragma unroll
    for (int ks = 0; ks < 4; ++ks) {
      short8 afr = *(const short8*)&arow[kc*128 + ks*32 + quad*8];
      #pragma unroll
      for (int nt = 0; nt < 4; ++nt)
        acc[nt] = __builtin_amdgcn_mfma_f32_16x16x32_bf16(
            afr, wf[((kc*4 + ks)*4 + nt)*64], acc[nt], 0, 0, 0);
    }

  __syncthreads();   // rsA/rsB ready (and ltf free)
  const float Ssum = rsA[0]+rsA[1]+rsA[2]+rsA[3];
  const float Qsum = rsB[0]+rsB[1]+rsB[2]+rsB[3];
  const float invn = 1.0f/(float)NPER;
  const float mean2 = Ssum*invn;
  const float var2  = fmaxf(Qsum*invn - mean2*mean2, 0.f);
  const float inv2  = 1.0f/sqrtf(var2 + EPSG);
  const float ms2   = inv2*mean2;

  #pragma unroll
  for (int nt = 0; nt < 4; ++nt) {
    int bl = nt*16 + l16;
    float cb = B2s[n0 + bl] - ms2*Sv[n0 + bl];
    #pragma unroll
    for (int r = 0; r < 4; ++r) {
      int tl = wv*16 + quad*4 + r;
      ltf[tl*68 + bl] = fmaf(inv2, acc[nt][r], cb);
    }
  }
  LDS_FENCE();   // wave-private 16-row stripes: write -> read within wave
  {
    int tr2 = tid >> 2, ck = (tid & 3) * 16;
    int tg = t0 + tr2;
    if (tg < Tdim) {
      const float* xr = &x[((size_t)m*Tdim + tg)*Bdim + n0 + ck];
      float* orow = &out[((size_t)m*Tdim + tg)*Bdim + n0 + ck];
      #pragma unroll
      for (int j = 0; j < 4; ++j) {
        float4 v = *(const float4*)&ltf[tr2*68 + ck + j*4];
        float4 rx = *(const float4*)&xr[j*4];
        v.x += rx.x; v.y += rx.y; v.z += rx.z; v.w += rx.w;
        *(float4*)&orow[j*4] = v;
      }
    }
  }
}

extern "C" void kernel_launch(void* const* d_in, const int* in_sizes, int n_in,
                              void* d_out, int out_size, void* d_ws, size_t ws_size,
                              hipStream_t stream)
{
  (void)in_sizes; (void)n_in; (void)out_size; (void)ws_size;
  const float* x    = (const float*)d_in[0];
  const float* w1   = (const float*)d_in[1];
  const float* a1   = (const float*)d_in[2];
  const float* g1   = (const float*)d_in[3];
  const float* b1   = (const float*)d_in[4];
  const float* odw  = (const float*)d_in[5];
  const float* aodc = (const float*)d_in[6];
  const float* opw  = (const float*)d_in[7];
  const float* aopc = (const float*)d_in[8];
  const float* dww  = (const float*)d_in[9];
  const float* dwb  = (const float*)d_in[10];
  const float* a2   = (const float*)d_in[11];
  const float* g2   = (const float*)d_in[12];
  const float* b2   = (const float*)d_in[13];
  const float* pww  = (const float*)d_in[14];
  float* out = (float*)d_out;

  char* ws = (char*)d_ws;
  const size_t OFF_P1  = 0;          // part1 [8,125] float2: 8000 B
  const size_t OFF_P2  = 8192;       // part2 [8,500] float2: 32000 B
  const size_t OFF_S   = 40960;      // Sv [128] f32: 512 B
  const size_t OFF_B2S = 41472;      // B2s [128] f32: 512 B
  const size_t OFF_W1R = 45056;      // w1r fragment bf16: 131072 B
  const size_t OFF_W2G = 176128;     // W2g [128,512] bf16 fragment order: 131072 B
  const size_t OFF_H   = 307200;     // Hbuf [8,4000,512] bf16: 32768000 B
  const size_t OFF_Y   = 33075200;   // Ybuf [8,4000,512] bf16: 32768000 B
  float2* part1 = (float2*)(ws + OFF_P1);
  float2* part2 = (float2*)(ws + OFF_P2);
  float*  Sv    = (float*)(ws + OFF_S);
  float*  B2s   = (float*)(ws + OFF_B2S);
  unsigned short* w1r  = (unsigned short*)(ws + OFF_W1R);
  unsigned short* W2g  = (unsigned short*)(ws + OFF_W2G);
  unsigned short* Hbuf = (unsigned short*)(ws + OFF_H);
  unsigned short* Ybuf = (unsigned short*)(ws + OFF_Y);

  k_prep  <<<dim3(64), 256, 0, stream>>>(w1, pww, g2, b2, w1r, W2g, Sv, B2s);
  k_conv1 <<<dim3(125, 8), 256, 0, stream>>>(x, w1r, a1, Hbuf, part1);
  k_deform<<<dim3(500, 8), 256, 0, stream>>>(Hbuf, part1, g1, b1, odw, aodc, opw, aopc, dww, dwb, a2, Ybuf, part2);
  k_out   <<<dim3(63, 2, 8), 256, 0, stream>>>(Ybuf, W2g, part2, Sv, B2s, x, out);
}

// Round 6
// 165.702 us; speedup vs baseline: 3.1700x; 1.0032x over previous
//
#include <hip/hip_runtime.h>

#define Mdim 8
#define Tdim 4000
#define Bdim 128
#define Hdim 512
#define NPER (Tdim*Hdim)
#define EPSG 1e-8f

typedef __attribute__((ext_vector_type(8))) short short8;
typedef __attribute__((ext_vector_type(4))) float floatx4;

static __device__ __forceinline__ float bits2f(unsigned short s) {
  union { unsigned int u; float f; } v; v.u = ((unsigned int)s) << 16; return v.f;
}
static __device__ __forceinline__ unsigned short f2bits(float f) {
  union { float f; unsigned int u; } v; v.f = f;
  unsigned int u = v.u;
  u += 0x7fffu + ((u >> 16) & 1u);   // RNE
  return (unsigned short)(u >> 16);
}
static __device__ __forceinline__ short8 pack8(const float4& a, const float4& b) {
  short8 v;
  v[0]=(short)f2bits(a.x); v[1]=(short)f2bits(a.y); v[2]=(short)f2bits(a.z); v[3]=(short)f2bits(a.w);
  v[4]=(short)f2bits(b.x); v[5]=(short)f2bits(b.y); v[6]=(short)f2bits(b.z); v[7]=(short)f2bits(b.w);
  return v;
}

// wave-local LDS fence: all lanes' ds ops drained; lockstep => covers cross-lane within wave
#define LDS_FENCE() do { \
  asm volatile("s_waitcnt lgkmcnt(0)" ::: "memory"); \
  __builtin_amdgcn_sched_barrier(0); \
} while (0)

// XCD-chunked task mapping: linear block id n -> XCD (n&7) owns m=(n&7) with
// contiguous tiles (n>>3). Dispatch round-robins blocks over the 8 XCDs, so
// adjacent-tile reuse (deform halo/gathers, out's half-pairs) hits local L2
// instead of Infinity Cache. Bijective: all grids are multiples of 8.

// ---------------- K0: one-time weight prep.
// blocks 0..31:  w1 [512,128] f32 -> fragment-ordered bf16 w1r.
// blocks 32..63: W2g[b,h] = pww[b,h]*g2[h] -> fragment-ordered bf16 (m-independent!);
//                S[b] = sum_h pww*g2, B2s[b] = sum_h pww*b2 (f32).
__global__ __launch_bounds__(256) void k_prep(
    const float* __restrict__ w1,
    const float* __restrict__ pww,
    const float* __restrict__ g2w,
    const float* __restrict__ b2w,
    unsigned short* __restrict__ w1r,
    unsigned short* __restrict__ W2g,
    float* __restrict__ Sv,
    float* __restrict__ B2s)
{
  const int tid = threadIdx.x;
  if (blockIdx.x < 32) {
    int i = blockIdx.x*256 + tid;            // 8192 short8 fragments
    int lane = i & 63, f = i >> 6;
    int nt = f & 3, ks = (f >> 2) & 3, hc = f >> 4;
    int h = hc*64 + nt*16 + (lane & 15);
    int c = ks*32 + (lane >> 4)*8;
    const float* src = &w1[(size_t)h*Bdim + c];
    float4 a = *(const float4*)src;
    float4 b = *(const float4*)(src + 4);
    *(short8*)&w1r[(size_t)i*8] = pack8(a, b);
  } else {
    const int b = (blockIdx.x - 32)*4 + (tid >> 6);   // one wave per b
    const int sub = tid & 63;
    const int j8 = sub*8;
    float pv[8], g2v[8], b2v[8];
    #pragma unroll
    for (int j = 0; j < 8; j += 4) {
      *(float4*)&pv[j]  = *(const float4*)&pww[(size_t)b*Hdim + j8 + j];
      *(float4*)&g2v[j] = *(const float4*)&g2w[j8 + j];
      *(float4*)&b2v[j] = *(const float4*)&b2w[j8 + j];
    }
    float sS = 0.f, sB = 0.f;
    short8 wv8;
    #pragma unroll
    for (int j = 0; j < 8; ++j) {
      float pg = pv[j]*g2v[j];
      sS += pg;
      sB += pv[j]*b2v[j];
      wv8[j] = (short)f2bits(pg);
    }
    // fragment address (m-independent): half=b>>6, nt=(b>>4)&3, l16=b&15;
    // kc=sub>>4, ks=(sub>>2)&3, quad=sub&3
    {
      int half = b >> 6, nt = (b >> 4) & 3, l16 = b & 15;
      int kc = sub >> 4, ks = (sub >> 2) & 3, quad = sub & 3;
      int lane = quad*16 + l16;
      size_t f = (((size_t)(half*4 + kc)*4 + ks)*4 + nt);
      *(short8*)&W2g[(f*64 + lane)*8] = wv8;
    }
    #pragma unroll
    for (int st = 32; st > 0; st >>= 1) { sS += __shfl_xor(sS, st); sB += __shfl_xor(sB, st); }
    if (sub == 0) { Sv[b] = sS; B2s[b] = sB; }
  }
}

// ---------------- K1: conv1 GEMM + PReLU + gLN1 partials -> Hbuf [M,T,H] bf16
// 32-t tiles (grid 1000); waves split h-halves; x read once; no block barriers in hot loop.
__global__ __launch_bounds__(256) void k_conv1(
    const float* __restrict__ x,
    const unsigned short* __restrict__ w1r,
    const float* __restrict__ a1p,
    unsigned short* __restrict__ Hbuf,
    float2* __restrict__ part1)
{
  __shared__ __align__(16) unsigned short ltile[4][16*72];
  __shared__ float red[512];

  const int tid = threadIdx.x;
  const int n = blockIdx.x + 125*blockIdx.y;   // XCD-chunked: m = n&7, tile = n>>3
  const int m  = n & 7;
  const int tile = n >> 3;
  const int t0 = tile * 32;
  const int lane = tid & 63, w = tid >> 6, quad = lane >> 4, l16 = lane & 15;
  const int tsub = w & 1, hh = w >> 1;
  const int tbase = t0 + tsub*16;            // 125*32 = 4000 exactly: no clamps needed
  const float* xrow = x + ((size_t)m*Tdim + tbase + l16)*Bdim;
  short8 afr[4];
  #pragma unroll
  for (int ks = 0; ks < 4; ++ks) {
    float4 fa = *(const float4*)&xrow[ks*32 + quad*8];
    float4 fb = *(const float4*)&xrow[ks*32 + quad*8 + 4];
    afr[ks] = pack8(fa, fb);
  }

  const float a1 = a1p[0];
  const short8* wf = (const short8*)w1r + lane;
  float lsum = 0.f, lss = 0.f;

  #pragma unroll
  for (int hc4 = 0; hc4 < 4; ++hc4) {
    const int hcg = hh*4 + hc4;
    floatx4 acc[4] = {};
    #pragma unroll
    for (int ks = 0; ks < 4; ++ks)
      #pragma unroll
      for (int nt = 0; nt < 4; ++nt)
        acc[nt] = __builtin_amdgcn_mfma_f32_16x16x32_bf16(
            afr[ks], wf[(hcg*16 + ks*4 + nt)*64], acc[nt], 0, 0, 0);

    #pragma unroll
    for (int nt = 0; nt < 4; ++nt) {
      int hl = nt*16 + l16;                  // C/D: col = lane&15
      #pragma unroll
      for (int r = 0; r < 4; ++r) {
        int tl = quad*4 + r;                 // C/D: row = quad*4+reg
        float v = acc[nt][r];
        v = v >= 0.f ? v : a1 * v;
        lsum += v; lss += v*v;
        ltile[w][tl*72 + hl] = f2bits(v);
      }
    }
    LDS_FENCE();   // wave-private transpose tile: writes -> cross-lane reads
    {
      int row = lane >> 2, ck = (lane & 3) * 16;
      unsigned short* dst = &Hbuf[((size_t)m*Tdim + tbase + row)*Hdim + hcg*64 + ck];
      *(short8*)&dst[0] = *(const short8*)&ltile[w][row*72 + ck];
      *(short8*)&dst[8] = *(const short8*)&ltile[w][row*72 + ck + 8];
    }
    LDS_FENCE();   // reads drained before next hc overwrites
  }

  red[tid] = lsum; red[256 + tid] = lss;
  __syncthreads();
  for (int s = 128; s > 0; s >>= 1) {
    if (tid < s) { red[tid] += red[tid + s]; red[256+tid] += red[256+tid+s]; }
    __syncthreads();
  }
  if (tid == 0)
    part1[(size_t)m*125 + tile] = make_float2(red[0], red[256]);
}

// ---------------- K2: fused offsets + deformable dw conv + PReLU2 + gLN2 partials -> Ybuf
// One wave per (m, 2 consecutive t), direct global gathers (proven fastest variant).
// XCD-chunked: each XCD owns one m, contiguous t -> halo/gather reuse is local-L2.
__global__ __launch_bounds__(256) void k_deform(
    const unsigned short* __restrict__ Hbuf,
    const float2* __restrict__ part1,
    const float* __restrict__ g1w,
    const float* __restrict__ b1w,
    const float* __restrict__ odw,
    const float* __restrict__ aodcp,
    const float* __restrict__ opw,
    const float* __restrict__ aopcp,
    const float* __restrict__ dww,
    const float* __restrict__ dwb,
    const float* __restrict__ a2p,
    unsigned short* __restrict__ Ybuf,
    float2* __restrict__ part2)
{
  __shared__ float s_stats[2];
  __shared__ float rsum[4], rss[4];
  const int tid = threadIdx.x, lane = tid & 63, w = tid >> 6;
  const int n = blockIdx.x + 500*blockIdx.y;   // XCD-chunked: m = n&7, tx = n>>3
  const int m  = n & 7;
  const int tx = n >> 3;                       // 0..499
  const int tb = tx*8 + w*2;                   // wave handles t = tb, tb+1
  const int c8 = lane*8;
  const unsigned short* base = Hbuf + (size_t)m*Tdim*Hdim;

  // issue offset-branch row loads EARLY (independent of stats barrier)
  short8 hrow[2][3];
  #pragma unroll
  for (int tt = 0; tt < 2; ++tt) {
    int t = tb + tt;
    int tm1 = (t == 0) ? 1 : t-1;
    int tp1 = (t == Tdim-1) ? Tdim-2 : t+1;
    hrow[tt][0] = *(const short8*)&base[(size_t)tm1*Hdim + c8];
    hrow[tt][1] = *(const short8*)&base[(size_t)t  *Hdim + c8];
    hrow[tt][2] = *(const short8*)&base[(size_t)tp1*Hdim + c8];
  }
  float g1v[8], b1v[8];
  #pragma unroll
  for (int j = 0; j < 8; j += 4) {
    *(float4*)&g1v[j] = *(const float4*)&g1w[c8 + j];
    *(float4*)&b1v[j] = *(const float4*)&b1w[c8 + j];
  }

  // inline reduce of part1 (125 entries) -> stats1
  if (tid < 64) {
    float s = 0.f, q = 0.f;
    for (int i = lane; i < 125; i += 64) {
      float2 p = part1[(size_t)m*125 + i];
      s += p.x; q += p.y;
    }
    #pragma unroll
    for (int st = 32; st > 0; st >>= 1) { s += __shfl_xor(s, st); q += __shfl_xor(q, st); }
    if (lane == 0) { s_stats[0] = s; s_stats[1] = q; }
  }
  __syncthreads();
  const float invn = 1.0f/(float)NPER;
  const float mean1 = s_stats[0]*invn;
  const float var1  = fmaxf(s_stats[1]*invn - mean1*mean1, 0.f);
  const float inv1  = 1.0f/sqrtf(var1 + EPSG);

  // ---- offset branch for both t ----
  float oa[2][3] = {};
  {
    const float aodc = aodcp[0];
    float wod[24], q0v[8], q1v[8], q2v[8];
    #pragma unroll
    for (int j = 0; j < 8; j += 4) {
      *(float4*)&q0v[j] = *(const float4*)&opw[c8 + j];
      *(float4*)&q1v[j] = *(const float4*)&opw[Hdim + c8 + j];
      *(float4*)&q2v[j] = *(const float4*)&opw[2*Hdim + c8 + j];
    }
    #pragma unroll
    for (int j = 0; j < 24; j += 4)
      *(float4*)&wod[j] = *(const float4*)&odw[c8*3 + j];

    #pragma unroll
    for (int j = 0; j < 8; ++j) {
      float A = g1v[j] * inv1;
      float C = b1v[j] - mean1*A;
      #pragma unroll
      for (int tt = 0; tt < 2; ++tt) {
        float fm = fmaf(A, bits2f((unsigned short)hrow[tt][0][j]), C);
        float fz = fmaf(A, bits2f((unsigned short)hrow[tt][1][j]), C);
        float fp = fmaf(A, bits2f((unsigned short)hrow[tt][2][j]), C);
        float d = fm*wod[j*3+0] + fz*wod[j*3+1] + fp*wod[j*3+2];
        d = d >= 0.f ? d : aodc*d;
        oa[tt][0] = fmaf(d, q0v[j], oa[tt][0]);
        oa[tt][1] = fmaf(d, q1v[j], oa[tt][1]);
        oa[tt][2] = fmaf(d, q2v[j], oa[tt][2]);
      }
    }
    #pragma unroll
    for (int s = 32; s > 0; s >>= 1) {
      #pragma unroll
      for (int tt = 0; tt < 2; ++tt) {
        oa[tt][0] += __shfl_xor(oa[tt][0], s);
        oa[tt][1] += __shfl_xor(oa[tt][1], s);
        oa[tt][2] += __shfl_xor(oa[tt][2], s);
      }
    }
  }

  // ---- tap params (wave-uniform) + gathers for both t ----
  const float aopc = aopcp[0];
  const float a2   = a2p[0];
  int I0[2][3], I1[2][3]; float G0[2][3], G1[2][3], GS[2][3];
  #pragma unroll
  for (int tt = 0; tt < 2; ++tt) {
    const float tf = (float)(tb + tt);
    #pragma unroll
    for (int k = 0; k < 3; ++k) {
      float off = oa[tt][k];
      off = off >= 0.f ? off : aopc*off;
      float pos = tf + (float)(2*k) + off;
      pos = fminf(fmaxf(pos, tf), tf + 4.0f);
      int U = (int)floorf(pos);
      if (U > Tdim + 2) U = Tdim + 2;        // Lp-2
      float Uf = (float)U;
      G0[tt][k] = fmaxf(0.f, 1.f - fabsf(Uf - pos));
      G1[tt][k] = fmaxf(0.f, 1.f - fabsf(Uf + 1.f - pos));
      GS[tt][k] = G0[tt][k] + G1[tt][k];
      int ia = U - 2; ia = ia < 0 ? -ia : ia; if (ia > Tdim-1) ia = 2*(Tdim-1) - ia;
      int ib = U - 1; ib = ib < 0 ? -ib : ib; if (ib > Tdim-1) ib = 2*(Tdim-1) - ib;
      I0[tt][k] = ia; I1[tt][k] = ib;
    }
  }

  // issue ALL 12 gather loads up front (both t's) for maximum MLP
  short8 s0v[2][3], s1v[2][3];
  #pragma unroll
  for (int tt = 0; tt < 2; ++tt)
    #pragma unroll
    for (int k = 0; k < 3; ++k) {
      s0v[tt][k] = *(const short8*)&base[(size_t)I0[tt][k]*Hdim + c8];
      s1v[tt][k] = *(const short8*)&base[(size_t)I1[tt][k]*Hdim + c8];
    }

  float bv[8], wd[24];
  #pragma unroll
  for (int j = 0; j < 8; j += 4)
    *(float4*)&bv[j] = *(const float4*)&dwb[c8 + j];
  #pragma unroll
  for (int j = 0; j < 24; j += 4)
    *(float4*)&wd[j] = *(const float4*)&dww[c8*3 + j];

  float lsum = 0.f, lss = 0.f;
  short8 yv[2];
  #pragma unroll
  for (int j = 0; j < 8; ++j) {
    float A = g1v[j] * inv1;
    float C = b1v[j] - mean1*A;
    float w0 = wd[j*3+0], w1 = wd[j*3+1], w2 = wd[j*3+2];
    #pragma unroll
    for (int tt = 0; tt < 2; ++tt) {
      float ybase = fmaf(C, w0*GS[tt][0] + w1*GS[tt][1] + w2*GS[tt][2], bv[j]);
      float t0s = fmaf(G1[tt][0], bits2f((unsigned short)s1v[tt][0][j]), G0[tt][0]*bits2f((unsigned short)s0v[tt][0][j]));
      float t1s = fmaf(G1[tt][1], bits2f((unsigned short)s1v[tt][1][j]), G0[tt][1]*bits2f((unsigned short)s0v[tt][1][j]));
      float t2s = fmaf(G1[tt][2], bits2f((unsigned short)s1v[tt][2][j]), G0[tt][2]*bits2f((unsigned short)s0v[tt][2][j]));
      float acc = w0*t0s + w1*t1s + w2*t2s;
      float y = fmaf(A, acc, ybase);
      float p = y >= 0.f ? y : a2*y;
      lsum += p; lss += p*p;
      yv[tt][j] = (short)f2bits(p);
    }
  }
  #pragma unroll
  for (int tt = 0; tt < 2; ++tt)
    *(short8*)&Ybuf[((size_t)m*Tdim + tb + tt)*Hdim + c8] = yv[tt];

  #pragma unroll
  for (int s = 32; s > 0; s >>= 1) {
    lsum += __shfl_xor(lsum, s);
    lss  += __shfl_xor(lss, s);
  }
  if (lane == 0) { rsum[w] = lsum; rss[w] = lss; }
  __syncthreads();
  if (tid == 0)
    part2[(size_t)m*500 + tx] =
      make_float2(rsum[0]+rsum[1]+rsum[2]+rsum[3], rss[0]+rss[1]+rss[2]+rss[3]);
}

// ---------------- K3: final GEMM Ybuf @ (pw*g2)^T; gLN2 applied as scalar affine epilogue.
// XCD-chunked: each XCD owns one m; the two n-halves of a tile run on adjacent
// blocks (same XCD) so the second read of each Ybuf row is a local-L2 hit.
__global__ __launch_bounds__(256) void k_out(
    const unsigned short* __restrict__ Ybuf,
    const unsigned short* __restrict__ W2g,
    const float2* __restrict__ part2,
    const float* __restrict__ Sv,
    const float* __restrict__ B2s,
    const float* __restrict__ x,
    float* __restrict__ out)
{
  __shared__ __align__(16) float ltf[64*68];
  __shared__ float rsA[4], rsB[4];
  const int tid = threadIdx.x;
  const int n = blockIdx.x + 63*(blockIdx.y + 2*blockIdx.z);  // 0..1007
  const int m = n & 7;
  const int r = n >> 3;                      // 0..125
  const int tile = r >> 1, half = r & 1;     // halves adjacent on same XCD
  const int t0 = tile*64;
  const int n0 = half*64;
  const int lane = tid & 63, wv = tid >> 6, quad = lane >> 4, l16 = lane & 15;

  // ---- inline gLN2 stats: all 4 waves split the 500 partials ----
  {
    float s = 0.f, q = 0.f;
    for (int i = tid; i < 500; i += 256) {
      float2 p = part2[(size_t)m*500 + i];
      s += p.x; q += p.y;
    }
    #pragma unroll
    for (int st = 32; st > 0; st >>= 1) { s += __shfl_xor(s, st); q += __shfl_xor(q, st); }
    if (lane == 0) { rsA[wv] = s; rsB[wv] = q; }
  }

  int tr = t0 + wv*16 + l16;
  int trc = tr < Tdim ? tr : Tdim-1;
  const unsigned short* arow = Ybuf + ((size_t)m*Tdim + trc)*Hdim;
  const short8* wf = (const short8*)W2g + (size_t)half*64*64 + lane;

  floatx4 acc[4] = {};
  #pragma unroll
  for (int kc = 0; kc < 4; ++kc)
    #pragma unroll
    for (int ks = 0; ks < 4; ++ks) {
      short8 afr = *(const short8*)&arow[kc*128 + ks*32 + quad*8];
      #pragma unroll
      for (int nt = 0; nt < 4; ++nt)
        acc[nt] = __builtin_amdgcn_mfma_f32_16x16x32_bf16(
            afr, wf[((kc*4 + ks)*4 + nt)*64], acc[nt], 0, 0, 0);
    }

  __syncthreads();   // rsA/rsB ready (and ltf free)
  const float Ssum = rsA[0]+rsA[1]+rsA[2]+rsA[3];
  const float Qsum = rsB[0]+rsB[1]+rsB[2]+rsB[3];
  const float invn = 1.0f/(float)NPER;
  const float mean2 = Ssum*invn;
  const float var2  = fmaxf(Qsum*invn - mean2*mean2, 0.f);
  const float inv2  = 1.0f/sqrtf(var2 + EPSG);
  const float ms2   = inv2*mean2;

  #pragma unroll
  for (int nt = 0; nt < 4; ++nt) {
    int bl = nt*16 + l16;
    float cb = B2s[n0 + bl] - ms2*Sv[n0 + bl];
    #pragma unroll
    for (int r2 = 0; r2 < 4; ++r2) {
      int tl = wv*16 + quad*4 + r2;
      ltf[tl*68 + bl] = fmaf(inv2, acc[nt][r2], cb);
    }
  }
  LDS_FENCE();   // wave-private 16-row stripes: write -> read within wave
  {
    int tr2 = tid >> 2, ck = (tid & 3) * 16;
    int tg = t0 + tr2;
    if (tg < Tdim) {
      const float* xr = &x[((size_t)m*Tdim + tg)*Bdim + n0 + ck];
      float* orow = &out[((size_t)m*Tdim + tg)*Bdim + n0 + ck];
      #pragma unroll
      for (int j = 0; j < 4; ++j) {
        float4 v = *(const float4*)&ltf[tr2*68 + ck + j*4];
        float4 rx = *(const float4*)&xr[j*4];
        v.x += rx.x; v.y += rx.y; v.z += rx.z; v.w += rx.w;
        *(float4*)&orow[j*4] = v;
      }
    }
  }
}

extern "C" void kernel_launch(void* const* d_in, const int* in_sizes, int n_in,
                              void* d_out, int out_size, void* d_ws, size_t ws_size,
                              hipStream_t stream)
{
  (void)in_sizes; (void)n_in; (void)out_size; (void)ws_size;
  const float* x    = (const float*)d_in[0];
  const float* w1   = (const float*)d_in[1];
  const float* a1   = (const float*)d_in[2];
  const float* g1   = (const float*)d_in[3];
  const float* b1   = (const float*)d_in[4];
  const float* odw  = (const float*)d_in[5];
  const float* aodc = (const float*)d_in[6];
  const float* opw  = (const float*)d_in[7];
  const float* aopc = (const float*)d_in[8];
  const float* dww  = (const float*)d_in[9];
  const float* dwb  = (const float*)d_in[10];
  const float* a2   = (const float*)d_in[11];
  const float* g2   = (const float*)d_in[12];
  const float* b2   = (const float*)d_in[13];
  const float* pww  = (const float*)d_in[14];
  float* out = (float*)d_out;

  char* ws = (char*)d_ws;
  const size_t OFF_P1  = 0;          // part1 [8,125] float2: 8000 B
  const size_t OFF_P2  = 8192;       // part2 [8,500] float2: 32000 B
  const size_t OFF_S   = 40960;      // Sv [128] f32: 512 B
  const size_t OFF_B2S = 41472;      // B2s [128] f32: 512 B
  const size_t OFF_W1R = 45056;      // w1r fragment bf16: 131072 B
  const size_t OFF_W2G = 176128;     // W2g [128,512] bf16 fragment order: 131072 B
  const size_t OFF_H   = 307200;     // Hbuf [8,4000,512] bf16: 32768000 B
  const size_t OFF_Y   = 33075200;   // Ybuf [8,4000,512] bf16: 32768000 B
  float2* part1 = (float2*)(ws + OFF_P1);
  float2* part2 = (float2*)(ws + OFF_P2);
  float*  Sv    = (float*)(ws + OFF_S);
  float*  B2s   = (float*)(ws + OFF_B2S);
  unsigned short* w1r  = (unsigned short*)(ws + OFF_W1R);
  unsigned short* W2g  = (unsigned short*)(ws + OFF_W2G);
  unsigned short* Hbuf = (unsigned short*)(ws + OFF_H);
  unsigned short* Ybuf = (unsigned short*)(ws + OFF_Y);

  k_prep  <<<dim3(64), 256, 0, stream>>>(w1, pww, g2, b2, w1r, W2g, Sv, B2s);
  k_conv1 <<<dim3(125, 8), 256, 0, stream>>>(x, w1r, a1, Hbuf, part1);
  k_deform<<<dim3(500, 8), 256, 0, stream>>>(Hbuf, part1, g1, b1, odw, aodc, opw, aopc, dww, dwb, a2, Ybuf, part2);
  k_out   <<<dim3(63, 2, 8), 256, 0, stream>>>(Ybuf, W2g, part2, Sv, B2s, x, out);
}